// Round 7
// baseline (401.345 us; speedup 1.0000x reference)
//
#include <hip/hip_runtime.h>
#include <math.h>

#define N 512
#define CS 384
#define CZ 128
#define NH 16
#define DH 24
#define HD 384
#define NN (N*N)
#define EPS 1e-5f

// ws layout (float offsets)
#define OFF_AN   0          // a_n [N][CS]
#define OFF_QT   196608     // qT [H][N][D] q-major (pre-scaled by 1/sqrt(24))
#define OFF_KT   393216     // ktd [H][D][N] d-major
#define OFF_VT   589824     // vtd [H][D][N] d-major
#define OFF_GT   786432     // gT [H][N][D] q-major (sigmoid applied)
#define OFF_OG   983040     // o*g [N][HD]
#define OFF_WZ2  1179648    // g_z*Wz transposed [H][CZ]
#define OFF_SH   1181696    // [H]
#define OFF_BH   1181712    // [H]
#define OFF_BIAS 1181728    // pair bias [H][N][N]

// ---------------- prep: Wz2[h][c] = g_z[c]*Wz[c][h]; Sh, Bh (parallel) ----------------
__global__ void prep_kernel(const float* __restrict__ g_z, const float* __restrict__ lnb_z,
                            const float* __restrict__ Wz, const float* __restrict__ bz,
                            float* __restrict__ wz2, float* __restrict__ sh, float* __restrict__ bh) {
    int t = threadIdx.x;
    for (int i = t; i < NH * CZ; i += 256) {
        int h = i >> 7, c = i & (CZ - 1);
        wz2[h * CZ + c] = g_z[c] * Wz[c * NH + h];
    }
    __shared__ float ls[NH][17], lb[NH][17];
    int h = t >> 4, seg = t & 15;
    float s = 0.f, b = 0.f;
    #pragma unroll
    for (int i = 0; i < 8; ++i) {
        int c = seg * 8 + i;
        float w = Wz[c * NH + h];
        s += g_z[c] * w;
        b += lnb_z[c] * w;
    }
    ls[h][seg] = s; lb[h][seg] = b;
    __syncthreads();
    if (t < NH) {
        float ss = 0.f, bb = 0.f;
        #pragma unroll
        for (int i = 0; i < 16; ++i) { ss += ls[t][i]; bb += lb[t][i]; }
        sh[t] = ss;
        bh[t] = bb + bz[t];
    }
}

// ---------------- LayerNorm of a: one block per row ----------------
__global__ void ln_a_kernel(const float* __restrict__ a, const float* __restrict__ g_a,
                            const float* __restrict__ b_a, float* __restrict__ an_out) {
    int r = blockIdx.x, t = threadIdx.x; // block 128
    const float* row = a + r * CS;
    float x0 = row[t], x1 = row[t + 128], x2 = row[t + 256];
    float s1 = x0 + x1 + x2;
    float s2 = x0 * x0 + x1 * x1 + x2 * x2;
    #pragma unroll
    for (int m = 1; m < 64; m <<= 1) {
        s1 += __shfl_xor(s1, m, 64);
        s2 += __shfl_xor(s2, m, 64);
    }
    __shared__ float ls1[2], ls2[2];
    if ((t & 63) == 0) { ls1[t >> 6] = s1; ls2[t >> 6] = s2; }
    __syncthreads();
    s1 = ls1[0] + ls1[1];
    s2 = ls2[0] + ls2[1];
    float mu = s1 * (1.f / CS);
    float var = s2 * (1.f / CS) - mu * mu;
    float rs = rsqrtf(var + EPS);
    float* an = an_out + r * CS;
    an[t]       = (x0 - mu) * rs * g_a[t]       + b_a[t];
    an[t + 128] = (x1 - mu) * rs * g_a[t + 128] + b_a[t + 128];
    an[t + 256] = (x2 - mu) * rs * g_a[t + 256] + b_a[t + 256];
}

// ---------------- q,k,v,g projections: weights in LDS, 2 rows/thread ----------------
// grid (48, 4), block 256. wave -> 8-col strip; lane -> rows m, m+256. Each weight
// ds_read_b128 feeds 2 independent row-chains.
__global__ void __launch_bounds__(256) qkvg_kernel(const float* __restrict__ Wq, const float* __restrict__ Wk,
                                                   const float* __restrict__ Wv, const float* __restrict__ Wg,
                                                   const float* __restrict__ bg, const float* __restrict__ an,
                                                   float* __restrict__ qt, float* __restrict__ ktd,
                                                   float* __restrict__ vtd, float* __restrict__ gt) {
    __shared__ __align__(16) float wlds[4 * 3072]; // 4 waves x (384 k x 8 cols) = 48 KB
    const int lane = threadIdx.x & 63;
    const int w = __builtin_amdgcn_readfirstlane(threadIdx.x >> 6);
    const int strip = blockIdx.x * 4 + w;     // 0..191
    const int n0 = strip * 8;
    const int sel = n0 / HD;                  // 0:q 1:k 2:v 3:g
    const int col = n0 % HD;
    const float* Wm = (sel == 0) ? Wq : (sel == 1) ? Wk : (sel == 2) ? Wv : Wg;

    // stage this wave's 8-col weight strip: wl[k*8 + j] = Wm[k*HD + col + j]
    float* wl = wlds + w * 3072;
    for (int idx = lane; idx < 3072; idx += 64) {
        int k = idx >> 3, j = idx & 7;
        wl[idx] = Wm[k * HD + col + j];
    }
    __syncthreads();

    const int m0 = blockIdx.y * 64 + lane;    // rows m0, m0+256
    const float* arow0 = an + m0 * CS;
    const float* arow1 = arow0 + 256 * CS;
    float acc0[8], acc1[8];
    #pragma unroll
    for (int j = 0; j < 8; ++j) { acc0[j] = 0.f; acc1[j] = 0.f; }
    for (int kb = 0; kb < CS; kb += 32) {
        float4 av0[8], av1[8];
        #pragma unroll
        for (int i = 0; i < 8; ++i) av0[i] = ((const float4*)(arow0 + kb))[i]; // full 128B line
        #pragma unroll
        for (int i = 0; i < 8; ++i) av1[i] = ((const float4*)(arow1 + kb))[i];
        #pragma unroll
        for (int i = 0; i < 8; ++i) {
            const float* wr = wl + (kb + i * 4) * 8; // 4 k-rows x 8 cols, uniform addr -> broadcast
            #pragma unroll
            for (int r = 0; r < 4; ++r) {
                float4 wa = ((const float4*)(wr + r * 8))[0];
                float4 wb = ((const float4*)(wr + r * 8))[1];
                float a0 = (r == 0) ? av0[i].x : (r == 1) ? av0[i].y : (r == 2) ? av0[i].z : av0[i].w;
                float a1 = (r == 0) ? av1[i].x : (r == 1) ? av1[i].y : (r == 2) ? av1[i].z : av1[i].w;
                acc0[0] += a0 * wa.x; acc0[1] += a0 * wa.y; acc0[2] += a0 * wa.z; acc0[3] += a0 * wa.w;
                acc0[4] += a0 * wb.x; acc0[5] += a0 * wb.y; acc0[6] += a0 * wb.z; acc0[7] += a0 * wb.w;
                acc1[0] += a1 * wa.x; acc1[1] += a1 * wa.y; acc1[2] += a1 * wa.z; acc1[3] += a1 * wa.w;
                acc1[4] += a1 * wb.x; acc1[5] += a1 * wb.y; acc1[6] += a1 * wb.z; acc1[7] += a1 * wb.w;
            }
        }
    }
    if (sel == 0) {
        #pragma unroll
        for (int j = 0; j < 8; ++j) {
            int c = col + j;
            int base = (c / DH) * N * DH + (c % DH);
            qt[base + m0 * DH]         = acc0[j] * 0.20412414523193153f; // 1/sqrt(24)
            qt[base + (m0 + 256) * DH] = acc1[j] * 0.20412414523193153f;
        }
    } else if (sel == 3) {
        #pragma unroll
        for (int j = 0; j < 8; ++j) {
            int c = col + j;
            int base = (c / DH) * N * DH + (c % DH);
            gt[base + m0 * DH]         = 1.f / (1.f + __expf(-(acc0[j] + bg[c])));
            gt[base + (m0 + 256) * DH] = 1.f / (1.f + __expf(-(acc1[j] + bg[c])));
        }
    } else {
        float* dst = (sel == 1) ? ktd : vtd;
        #pragma unroll
        for (int j = 0; j < 8; ++j) {
            int c = col + j;
            dst[c * N + m0]       = acc0[j]; // [h][d][n], lane m contiguous
            dst[c * N + m0 + 256] = acc1[j];
        }
    }
}

// ---------------- fused z-LN + z_n@Wz -> pair bias; weights in LDS, 4 rows/thread ----------------
// grid 256 blocks x 256 threads; thread handles rows r0 = b*1024+t, +256, +512, +768.
// Each weight ds_read_b128 feeds 16 FMAs (4 independent row-chains).
__global__ void __launch_bounds__(256) pairbias_kernel(const float* __restrict__ z,
                                                       const float* __restrict__ wz2,
                                                       const float* __restrict__ sh,
                                                       const float* __restrict__ bh,
                                                       float* __restrict__ bias) {
    __shared__ __align__(16) float wl[NH * CZ + 32]; // 8.2 KB
    const int t = threadIdx.x;
    for (int i = t; i < NH * CZ; i += 256) wl[i] = wz2[i];
    if (t < NH) { wl[NH * CZ + t] = sh[t]; wl[NH * CZ + 16 + t] = bh[t]; }
    __syncthreads();

    const int r0 = blockIdx.x * 1024 + t; // rows r0 + {0,256,512,768}
    const float* zr = z + (size_t)r0 * CZ;

    float dots[4][NH];
    #pragma unroll
    for (int r = 0; r < 4; ++r)
        #pragma unroll
        for (int h = 0; h < NH; ++h) dots[r][h] = 0.f;
    float s1[4] = {0.f, 0.f, 0.f, 0.f}, s2[4] = {0.f, 0.f, 0.f, 0.f};

    #pragma unroll
    for (int cb = 0; cb < CZ; cb += 32) {
        float4 zv[4][8];
        #pragma unroll
        for (int r = 0; r < 4; ++r)
            #pragma unroll
            for (int i = 0; i < 8; ++i)
                zv[r][i] = ((const float4*)(zr + r * 256 * CZ + cb))[i]; // 128B line/lane
        #pragma unroll
        for (int r = 0; r < 4; ++r)
            #pragma unroll
            for (int i = 0; i < 8; ++i) {
                s1[r] += zv[r][i].x + zv[r][i].y + zv[r][i].z + zv[r][i].w;
                s2[r] += zv[r][i].x * zv[r][i].x + zv[r][i].y * zv[r][i].y
                       + zv[r][i].z * zv[r][i].z + zv[r][i].w * zv[r][i].w;
            }
        #pragma unroll
        for (int h = 0; h < NH; ++h) {
            const float* wrow = wl + h * CZ + cb; // uniform addr -> LDS broadcast
            float d0 = dots[0][h], d1 = dots[1][h], d2 = dots[2][h], d3 = dots[3][h];
            #pragma unroll
            for (int i = 0; i < 8; ++i) {
                float4 wv = *(const float4*)(wrow + i * 4);
                d0 += zv[0][i].x * wv.x + zv[0][i].y * wv.y + zv[0][i].z * wv.z + zv[0][i].w * wv.w;
                d1 += zv[1][i].x * wv.x + zv[1][i].y * wv.y + zv[1][i].z * wv.z + zv[1][i].w * wv.w;
                d2 += zv[2][i].x * wv.x + zv[2][i].y * wv.y + zv[2][i].z * wv.z + zv[2][i].w * wv.w;
                d3 += zv[3][i].x * wv.x + zv[3][i].y * wv.y + zv[3][i].z * wv.z + zv[3][i].w * wv.w;
            }
            dots[0][h] = d0; dots[1][h] = d1; dots[2][h] = d2; dots[3][h] = d3;
        }
    }
    float rr[4], mu[4];
    #pragma unroll
    for (int r = 0; r < 4; ++r) {
        mu[r] = s1[r] * (1.f / CZ);
        float var = s2[r] * (1.f / CZ) - mu[r] * mu[r];
        rr[r] = rsqrtf(var + EPS);
    }
    #pragma unroll
    for (int h = 0; h < NH; ++h) {
        float shh = wl[NH * CZ + h], bhh = wl[NH * CZ + 16 + h];
        #pragma unroll
        for (int r = 0; r < 4; ++r)
            bias[h * NN + r0 + r * 256] = rr[r] * (dots[r][h] - mu[r] * shh) + bhh;
    }
}

// ---------------- attention: 2 q per wave, 32 lanes x 4 k each, d-major K/V ----------------
__global__ void __launch_bounds__(256) attn_kernel(const float* __restrict__ qt, const float* __restrict__ ktd,
                                                   const float* __restrict__ vtd, const float* __restrict__ gt,
                                                   const float* __restrict__ bias, float* __restrict__ og) {
    const int lane = threadIdx.x & 63;
    const int w = __builtin_amdgcn_readfirstlane(threadIdx.x >> 6);
    const int qhalf = lane >> 5;     // 0/1
    const int kl = lane & 31;        // 0..31 -> 4 consecutive k each
    const int h = blockIdx.y;
    const int q = blockIdx.x * 8 + w * 2 + qhalf;
    const float* qT  = qt  + h * N * DH;
    const float* kTd = ktd + h * DH * N;
    const float* vTd = vtd + h * DH * N;

    float qv[DH];
    #pragma unroll
    for (int d6 = 0; d6 < 6; ++d6) {
        float4 t4 = ((const float4*)(qT + q * DH))[d6];
        qv[d6 * 4 + 0] = t4.x; qv[d6 * 4 + 1] = t4.y; qv[d6 * 4 + 2] = t4.z; qv[d6 * 4 + 3] = t4.w;
    }
    float sc[16];
    #pragma unroll
    for (int t = 0; t < 4; ++t) {
        const int kbase = t * 128 + kl * 4;
        float4 b4 = *(const float4*)(bias + h * NN + q * N + kbase); // coalesced
        float s0 = b4.x, s1 = b4.y, s2 = b4.z, s3 = b4.w;
        #pragma unroll
        for (int d = 0; d < DH; ++d) {
            float4 k4 = *(const float4*)(kTd + d * N + kbase); // 32 lanes contiguous
            float qd = qv[d];
            s0 += qd * k4.x; s1 += qd * k4.y; s2 += qd * k4.z; s3 += qd * k4.w;
        }
        sc[t * 4 + 0] = s0; sc[t * 4 + 1] = s1; sc[t * 4 + 2] = s2; sc[t * 4 + 3] = s3;
    }
    float mx = sc[0];
    #pragma unroll
    for (int t = 1; t < 16; ++t) mx = fmaxf(mx, sc[t]);
    #pragma unroll
    for (int m = 1; m < 32; m <<= 1) mx = fmaxf(mx, __shfl_xor(mx, m, 64));
    float sum = 0.f;
    #pragma unroll
    for (int t = 0; t < 16; ++t) { sc[t] = __expf(sc[t] - mx); sum += sc[t]; }
    #pragma unroll
    for (int m = 1; m < 32; m <<= 1) sum += __shfl_xor(sum, m, 64);
    float inv = 1.f / sum;
    #pragma unroll
    for (int t = 0; t < 16; ++t) sc[t] *= inv;
    float acc[DH];
    #pragma unroll
    for (int d = 0; d < DH; ++d) acc[d] = 0.f;
    #pragma unroll
    for (int t = 0; t < 4; ++t) {
        const int kbase = t * 128 + kl * 4;
        float p0 = sc[t * 4 + 0], p1 = sc[t * 4 + 1], p2 = sc[t * 4 + 2], p3 = sc[t * 4 + 3];
        #pragma unroll
        for (int d = 0; d < DH; ++d) {
            float4 v4 = *(const float4*)(vTd + d * N + kbase);
            acc[d] += p0 * v4.x + p1 * v4.y + p2 * v4.z + p3 * v4.w;
        }
    }
    #pragma unroll
    for (int m = 1; m < 32; m <<= 1) {
        #pragma unroll
        for (int d = 0; d < DH; ++d) acc[d] += __shfl_xor(acc[d], m, 64);
    }
    float o = 0.f;
    #pragma unroll
    for (int d = 0; d < DH; ++d) o = (kl == d) ? acc[d] : o;
    if (kl < DH) {
        float g = gt[h * N * DH + q * DH + kl];
        og[q * HD + h * DH + kl] = o * g;
    }
}

// ---------------- out = og @ Wo + bo: weights staged in LDS ----------------
// grid (24, 8), block 256. wave -> 4-col strip; lane -> row.
__global__ void __launch_bounds__(256) out_gemm_kernel(const float* __restrict__ Wo, const float* __restrict__ bo,
                                                       const float* __restrict__ og, float* __restrict__ out) {
    __shared__ __align__(16) float wlds[4 * 1536]; // 4 waves x (384 k x 4 cols) = 24 KB
    const int lane = threadIdx.x & 63;
    const int w = __builtin_amdgcn_readfirstlane(threadIdx.x >> 6);
    const int strip = blockIdx.x * 4 + w;  // 0..95
    const int c0 = strip * 4;

    float* wl = wlds + w * 1536;
    for (int idx = lane; idx < 1536; idx += 64) {
        int k = idx >> 2, j = idx & 3;
        wl[idx] = Wo[k * CS + c0 + j];
    }
    __syncthreads();

    const int m = blockIdx.y * 64 + lane;
    const float* orow = og + m * HD;
    float acc[4];
    #pragma unroll
    for (int j = 0; j < 4; ++j) acc[j] = 0.f;
    for (int kb = 0; kb < HD; kb += 32) {
        float4 av[8];
        #pragma unroll
        for (int i = 0; i < 8; ++i) av[i] = ((const float4*)(orow + kb))[i];
        #pragma unroll
        for (int i = 0; i < 8; ++i) {
            const float* wr = wl + (kb + i * 4) * 4; // 4 k-rows x 4 cols, uniform -> broadcast
            #pragma unroll
            for (int r = 0; r < 4; ++r) {
                float4 wv = *(const float4*)(wr + r * 4);
                float ar = (r == 0) ? av[i].x : (r == 1) ? av[i].y : (r == 2) ? av[i].z : av[i].w;
                acc[0] += ar * wv.x; acc[1] += ar * wv.y; acc[2] += ar * wv.z; acc[3] += ar * wv.w;
            }
        }
    }
    #pragma unroll
    for (int j = 0; j < 4; ++j) out[m * CS + c0 + j] = acc[j] + bo[c0 + j];
}

extern "C" void kernel_launch(void* const* d_in, const int* in_sizes, int n_in,
                              void* d_out, int out_size, void* d_ws, size_t ws_size,
                              hipStream_t stream) {
    const float* a    = (const float*)d_in[0];
    const float* z    = (const float*)d_in[1];
    const float* g_a  = (const float*)d_in[2];
    const float* b_a  = (const float*)d_in[3];
    const float* g_z  = (const float*)d_in[4];
    const float* b_z  = (const float*)d_in[5];
    const float* Wz   = (const float*)d_in[6];
    const float* bz   = (const float*)d_in[7];
    const float* Wq   = (const float*)d_in[8];
    const float* Wk   = (const float*)d_in[9];
    const float* Wv   = (const float*)d_in[10];
    const float* Wg   = (const float*)d_in[11];
    const float* bg   = (const float*)d_in[12];
    const float* Wo   = (const float*)d_in[13];
    const float* bo   = (const float*)d_in[14];
    float* ws  = (float*)d_ws;
    float* out = (float*)d_out;

    float* an   = ws + OFF_AN;
    float* qt   = ws + OFF_QT;
    float* ktd  = ws + OFF_KT;
    float* vtd  = ws + OFF_VT;
    float* gt   = ws + OFF_GT;
    float* ogp  = ws + OFF_OG;
    float* wz2  = ws + OFF_WZ2;
    float* shp  = ws + OFF_SH;
    float* bhp  = ws + OFF_BH;
    float* bias = ws + OFF_BIAS;

    hipLaunchKernelGGL(prep_kernel,     dim3(1),      dim3(256), 0, stream, g_z, b_z, Wz, bz, wz2, shp, bhp);
    hipLaunchKernelGGL(ln_a_kernel,     dim3(512),    dim3(128), 0, stream, a, g_a, b_a, an);
    hipLaunchKernelGGL(qkvg_kernel,     dim3(48, 4),  dim3(256), 0, stream, Wq, Wk, Wv, Wg, bg, an, qt, ktd, vtd, gt);
    hipLaunchKernelGGL(pairbias_kernel, dim3(256),    dim3(256), 0, stream, z, wz2, shp, bhp, bias);
    hipLaunchKernelGGL(attn_kernel,     dim3(64, 16), dim3(256), 0, stream, qt, ktd, vtd, gt, bias, ogp);
    hipLaunchKernelGGL(out_gemm_kernel, dim3(24, 8),  dim3(256), 0, stream, Wo, bo, ogp, out);
}